// Round 3
// baseline (118.797 us; speedup 1.0000x reference)
//
#include <hip/hip_runtime.h>

// ---------------------------------------------------------------------------
// RandomForest: 100 trees, depth 5, D=256, B=8192, C=64.
// Three kernels: prep (W image + bf16 leaves), forest_all (GEMM + traversal +
// in-lane fp64 fixup), leaf_gather (bf16 leaves).
// Harness floor model: two 256MiB poison fills ~85.3us are inside the timed
// window; controllable GPU work was ~23us in r1. This round: ~16us.
//  * prep-X dropped: forest splits raw f32 X into bf16 hi/lo in registers via
//    v_and + exact v_sub + v_perm_b32 truncating pack (resid <= 2^-16|x|,
//    sigma_z ~ 1.5e-4, TAU=2e-3 = 13 sigma).
//  * W image: RNE hi/lo bf16, pre-swizzled for zero-VALU global_load_lds
//    staging (r0/r1 proven layout).
//  * fixup in-lane (r2 proven), no queue/qcount, no memset.
//  * leaves bf16 (r0/r1 proven, absmax 2^-9 accepted).
// ---------------------------------------------------------------------------

typedef __bf16 bf16;
typedef __attribute__((ext_vector_type(8))) __bf16 bf16x8;
typedef __attribute__((ext_vector_type(4))) float f32x4;
typedef __attribute__((ext_vector_type(4))) unsigned int u32x4;

#define NTREES 100
#define NB     8192
#define ND     256
#define NNODES 31
#define NLEAF  32
#define NCLS   64
#define TAU    2.0e-3f

static __device__ __forceinline__ void gload16(const void* g, void* l) {
    __builtin_amdgcn_global_load_lds(
        (const __attribute__((address_space(1))) void*)g,
        (__attribute__((address_space(3))) void*)l, 16, 0, 0);
}

// Truncating bf16 hi/lo split of 8 f32: hi = top16(x) (toward-zero),
// r = x - hi (exact), lo = top16(r). Packs via v_perm_b32.
static __device__ __forceinline__ void split8(const f32x4 v0, const f32x4 v1,
                                              bf16x8* hi, bf16x8* lo) {
    u32x4 b0 = __builtin_bit_cast(u32x4, v0);
    u32x4 b1 = __builtin_bit_cast(u32x4, v1);
    u32x4 h0 = b0 & 0xFFFF0000u;
    u32x4 h1 = b1 & 0xFFFF0000u;
    f32x4 r0 = v0 - __builtin_bit_cast(f32x4, h0);
    f32x4 r1 = v1 - __builtin_bit_cast(f32x4, h1);
    u32x4 c0 = __builtin_bit_cast(u32x4, r0);
    u32x4 c1 = __builtin_bit_cast(u32x4, r1);
    u32x4 hp, lp;
    hp[0] = __builtin_amdgcn_perm(b0[1], b0[0], 0x07060302u);
    hp[1] = __builtin_amdgcn_perm(b0[3], b0[2], 0x07060302u);
    hp[2] = __builtin_amdgcn_perm(b1[1], b1[0], 0x07060302u);
    hp[3] = __builtin_amdgcn_perm(b1[3], b1[2], 0x07060302u);
    lp[0] = __builtin_amdgcn_perm(c0[1], c0[0], 0x07060302u);
    lp[1] = __builtin_amdgcn_perm(c0[3], c0[2], 0x07060302u);
    lp[2] = __builtin_amdgcn_perm(c1[1], c1[0], 0x07060302u);
    lp[3] = __builtin_amdgcn_perm(c1[3], c1[2], 0x07060302u);
    *hi = __builtin_bit_cast(bf16x8, hp);
    *lo = __builtin_bit_cast(bf16x8, lp);
}

// Register-select traversal (reference node idx = 2*idx + d, so level-l node
// is the l-bit big-endian decision prefix; only nodes 0..15 are ever read).
static __device__ __forceinline__ int traverse(const float z[16], float* mn_out) {
    float a0 = z[0];
    bool d0 = a0 <= 0.f;
    float a1 = d0 ? z[1] : z[0];
    bool d1 = a1 <= 0.f;
    float a2 = d0 ? (d1 ? z[3] : z[2]) : (d1 ? z[1] : z[0]);
    bool d2 = a2 <= 0.f;
    float m0 = d2 ? z[1] : z[0], m1 = d2 ? z[3] : z[2];
    float m2 = d2 ? z[5] : z[4], m3 = d2 ? z[7] : z[6];
    float p0 = d1 ? m1 : m0, p1 = d1 ? m3 : m2;
    float a3 = d0 ? p1 : p0;
    bool d3 = a3 <= 0.f;
    float n0 = d3 ? z[1] : z[0],  n1 = d3 ? z[3] : z[2];
    float n2 = d3 ? z[5] : z[4],  n3 = d3 ? z[7] : z[6];
    float n4 = d3 ? z[9] : z[8],  n5 = d3 ? z[11] : z[10];
    float n6 = d3 ? z[13] : z[12], n7 = d3 ? z[15] : z[14];
    float q0 = d2 ? n1 : n0, q1 = d2 ? n3 : n2;
    float q2 = d2 ? n5 : n4, q3 = d2 ? n7 : n6;
    float r0 = d1 ? q1 : q0, r1 = d1 ? q3 : q2;
    float a4 = d0 ? r1 : r0;
    bool d4 = a4 <= 0.f;
    *mn_out = fminf(fminf(fminf(fabsf(a0), fabsf(a1)),
                          fminf(fabsf(a2), fabsf(a3))), fabsf(a4));
    return ((int)d0 << 4) | ((int)d1 << 3) | ((int)d2 << 2)
         | ((int)d3 << 1) | (int)d4;
}

// ---- K1: prep ---------------------------------------------------------------
// blocks 0..207: W image, 13 tg x [4 kq x (hi 16KB | lo 16KB)];
//   within: row*64 + (oct^(row&7))*8 elems, oct = k-octet within quarter.
// blocks 208..1007: leaves -> bf16.
__global__ void prep(const float* __restrict__ wf, const float* __restrict__ lv,
                     bf16* __restrict__ wimg, bf16* __restrict__ lv16) {
    if (blockIdx.x < 208) {
        int i = blockIdx.x * 256 + threadIdx.x;  // 0..53247
        int oct_g = i & 31;          // global k-octet 0..31
        int row   = (i >> 5) & 127;  // B row 0..127
        int tg    = i >> 12;         // tree group 0..12
        int tree  = tg * 8 + (row >> 4), node = row & 15;
        bf16x8 h8, l8;
        if (tree < NTREES) {
            const float* src = wf + ((size_t)tree * NNODES + node) * ND + oct_g * 8;
#pragma unroll
            for (int e = 0; e < 8; ++e) {
                float f = src[e];
                bf16 h = (bf16)f;
                h8[e] = h;
                l8[e] = (bf16)(f - (float)h);
            }
        } else {
#pragma unroll
            for (int e = 0; e < 8; ++e) { h8[e] = (bf16)0.f; l8[e] = (bf16)0.f; }
        }
        int kq = oct_g >> 3, oct = oct_g & 7, cp = oct ^ (row & 7);
        size_t b = (size_t)tg * 65536 + (size_t)kq * 16384 + row * 64 + cp * 8;
        *(bf16x8*)(wimg + b)        = h8;   // hi
        *(bf16x8*)(wimg + b + 8192) = l8;   // lo
    } else {
        int i = (blockIdx.x - 208) * 256 + threadIdx.x;  // 0..204799
        lv16[i] = (bf16)lv[i];
    }
}

// ---- K2: GEMM + traversal + in-lane fixup -----------------------------------
// block: 256 samples x 8 trees (128 node-cols). 4 waves, each M=64, N=128.
__global__ __launch_bounds__(256, 2) void forest_all(
    const float* __restrict__ x,      // [8192][256] raw f32
    const bf16* __restrict__ wimg,    // pre-swizzled W image
    const float* __restrict__ wf,     // raw W (for fp64 fixup)
    const float* __restrict__ bias,   // [100][31]
    unsigned char* __restrict__ idxb) // [8192][100]
{
    __shared__ char lds[65536];        // two 32KB B buffers; scr overlays buf0

    const int tid  = threadIdx.x;
    const int wave = tid >> 6;
    const int lane = tid & 63;
    const int m    = lane & 15;
    const int q    = lane >> 4;

    const int lin  = blockIdx.x + gridDim.x * blockIdx.y;   // 0..415
    const int xcd  = lin & 7;
    const int slot = lin >> 3;         // 0..51
    const int mg   = xcd * 4 + (slot / 13);
    const int tg   = slot % 13;        // tree-group of 8 (tg 12: 4 real)

    f32x4 acc[4][8];
#pragma unroll
    for (int mi = 0; mi < 4; ++mi)
#pragma unroll
        for (int ni = 0; ni < 8; ++ni)
            acc[mi][ni] = (f32x4){0.f, 0.f, 0.f, 0.f};

    // A source: row(mi) = mg*256 + wave*64 + mi*16 + m ; dims = kk*32 + q*8
    const float* xbase = x + (size_t)(mg * 256 + wave * 64 + m) * ND + q * 8;
    const bf16* wsrc = wimg + (size_t)tg * 65536;

    // ---- stage kq=0 into buf0 (async, zero VALU), prefetch raw A for kk=0
#pragma unroll
    for (int j = 0; j < 8; ++j) {
        int idx = j * 256 + tid;           // 2048 16B chunks = 32KB
        gload16(wsrc + idx * 8, lds + idx * 16);
    }
    f32x4 raw[4][2];
#pragma unroll
    for (int mi = 0; mi < 4; ++mi) {
        raw[mi][0] = *(const f32x4*)(xbase + mi * 4096);
        raw[mi][1] = *(const f32x4*)(xbase + mi * 4096 + 4);
    }
    __syncthreads();

#pragma unroll
    for (int kq = 0; kq < 4; ++kq) {
        const bf16* bufc = (const bf16*)(lds + (kq & 1) * 32768);
        if (kq < 3) {                      // async-stage next quarter
            char* bufn = lds + ((kq + 1) & 1) * 32768;
#pragma unroll
            for (int j = 0; j < 8; ++j) {
                int idx = j * 256 + tid;
                gload16(wsrc + (size_t)(kq + 1) * 16384 + idx * 8, bufn + idx * 16);
            }
        }
#pragma unroll
        for (int kkq = 0; kkq < 2; ++kkq) {
            const int kk = kq * 2 + kkq;
            bf16x8 cah[4], cal[4];
#pragma unroll
            for (int mi = 0; mi < 4; ++mi)
                split8(raw[mi][0], raw[mi][1], &cah[mi], &cal[mi]);
            if (kk < 7) {                  // prefetch next raw A batch
#pragma unroll
                for (int mi = 0; mi < 4; ++mi) {
                    raw[mi][0] = *(const f32x4*)(xbase + mi * 4096 + (kk + 1) * 32);
                    raw[mi][1] = *(const f32x4*)(xbase + mi * 4096 + (kk + 1) * 32 + 4);
                }
            }
#pragma unroll
            for (int ni = 0; ni < 8; ++ni) {
                const int n  = ni * 16 + m;
                const int cp = (kkq * 4 + q) ^ (m & 7);
                bf16x8 bh = *(const bf16x8*)(bufc + n * 64 + cp * 8);
                bf16x8 bl = *(const bf16x8*)(bufc + 8192 + n * 64 + cp * 8);
#pragma unroll
                for (int mi = 0; mi < 4; ++mi) {
                    acc[mi][ni] = __builtin_amdgcn_mfma_f32_16x16x32_bf16(cal[mi], bh, acc[mi][ni], 0, 0, 0);
                    acc[mi][ni] = __builtin_amdgcn_mfma_f32_16x16x32_bf16(cah[mi], bl, acc[mi][ni], 0, 0, 0);
                    acc[mi][ni] = __builtin_amdgcn_mfma_f32_16x16x32_bf16(cah[mi], bh, acc[mi][ni], 0, 0, 0);
                }
            }
        }
        __syncthreads();   // next buffer staged AND current fully consumed
    }

    // ---- epilogue: per-wave transpose via LDS, traversal, in-lane fp64 fixup
    float biasv[8];
#pragma unroll
    for (int ni = 0; ni < 8; ++ni) {
        int tree = tg * 8 + ni;
        biasv[ni] = (tree < NTREES) ? bias[(size_t)tree * NNODES + m] : 0.f;
    }

    float* ws_ = (float*)lds + wave * 1280;    // 64 rows x 20 floats per wave
    const int sg = mg * 256 + wave * 64 + lane;
    unsigned int pk0 = 0, pk1 = 0;
#pragma unroll
    for (int ni = 0; ni < 8; ++ni) {
#pragma unroll
        for (int mi = 0; mi < 4; ++mi)
#pragma unroll
            for (int r = 0; r < 4; ++r)
                ws_[(mi * 16 + q * 4 + r) * 20 + m] = acc[mi][ni][r] + biasv[ni];
        f32x4 z0 = *(f32x4*)&ws_[lane * 20];
        f32x4 z1 = *(f32x4*)&ws_[lane * 20 + 4];
        f32x4 z2 = *(f32x4*)&ws_[lane * 20 + 8];
        f32x4 z3 = *(f32x4*)&ws_[lane * 20 + 12];
        float z[16] = {z0[0], z0[1], z0[2], z0[3], z1[0], z1[1], z1[2], z1[3],
                       z2[0], z2[1], z2[2], z2[3], z3[0], z3[1], z3[2], z3[3]};
        float mn;
        int leaf = traverse(z, &mn);
        const int tree = tg * 8 + ni;
        if (tree < NTREES && mn < TAU) {       // rare: ~13 sigma guard band
            const float* xr = x + (size_t)sg * ND;
            float zc[16];
#pragma unroll
            for (int nd = 0; nd < 16; ++nd) zc[nd] = z[nd];
#pragma unroll
            for (int nd = 0; nd < 16; ++nd) {
                if (fabsf(z[nd]) < TAU) {
                    const float* wr = wf + ((size_t)tree * NNODES + nd) * ND;
                    double s0 = 0.0, s1 = 0.0;
#pragma unroll 4
                    for (int k2 = 0; k2 < 32; ++k2) {
                        f32x4 xv = *(const f32x4*)(xr + k2 * 8);
                        f32x4 wv = *(const f32x4*)(wr + k2 * 8);
                        f32x4 xu = *(const f32x4*)(xr + k2 * 8 + 4);
                        f32x4 wu = *(const f32x4*)(wr + k2 * 8 + 4);
                        s0 += (double)xv[0] * wv[0] + (double)xv[1] * wv[1]
                            + (double)xv[2] * wv[2] + (double)xv[3] * wv[3];
                        s1 += (double)xu[0] * wu[0] + (double)xu[1] * wu[1]
                            + (double)xu[2] * wu[2] + (double)xu[3] * wu[3];
                    }
                    double zt = s0 + s1 + (double)bias[(size_t)tree * NNODES + nd];
                    zc[nd] = (zt <= 0.0) ? -1.f : 1.f;
                }
            }
            float mn2;
            leaf = traverse(zc, &mn2);
        }
        if (ni < 4) pk0 |= (unsigned)leaf << (8 * ni);
        else        pk1 |= (unsigned)leaf << (8 * (ni - 4));
    }
    unsigned char* dst = idxb + (size_t)sg * NTREES + tg * 8;
    *(unsigned int*)dst = pk0;
    if (tg < 12) *(unsigned int*)(dst + 4) = pk1;
}

// ---- K3: leaf gather (bf16 leaves) + forest mean ----------------------------
__global__ void leaf_gather(const unsigned char* __restrict__ idxb,
                            const bf16* __restrict__ lv16,
                            float* __restrict__ out) {
    const int wave = threadIdx.x >> 6;
    const int lane = threadIdx.x & 63;
    const int s = blockIdx.x * 4 + wave;
    unsigned int rw = 0;
    if (lane < 25) rw = *(const unsigned int*)(idxb + (size_t)s * NTREES + lane * 4);
    float acc = 0.f;
#pragma unroll 10
    for (int t = 0; t < NTREES; ++t) {
        unsigned int wrd = __shfl(rw, t >> 2);
        int li = (wrd >> ((t & 3) * 8)) & 255;
        acc += (float)lv16[((size_t)t * NLEAF + li) * NCLS + lane];
    }
    out[(size_t)s * NCLS + lane] = acc * 0.01f;
}

// ---------------------------------------------------------------------------
extern "C" void kernel_launch(void* const* d_in, const int* in_sizes, int n_in,
                              void* d_out, int out_size, void* d_ws, size_t ws_size,
                              hipStream_t stream) {
    const float* x  = (const float*)d_in[0];   // [8192,256]
    const float* nw = (const float*)d_in[1];   // [100,31,256]
    const float* nb = (const float*)d_in[2];   // [100,31]
    const float* lv = (const float*)d_in[3];   // [100,32,64]
    float* out = (float*)d_out;

    char* ws = (char*)d_ws;
    bf16* wimg = (bf16*)(ws + 0);                          // 1,703,936
    unsigned char* idxb = (unsigned char*)(ws + 1703936);  //   819,200
    bf16* lv16 = (bf16*)(ws + 2523136);                    //   409,600
    if (ws_size < (size_t)2932736) return;

    prep<<<1008, 256, 0, stream>>>(nw, lv, wimg, lv16);
    forest_all<<<dim3(13, 32), 256, 0, stream>>>(x, wimg, nw, nb, idxb);
    leaf_gather<<<NB / 4, 256, 0, stream>>>(idxb, lv16, out);
}